// Round 2
// baseline (224.577 us; speedup 1.0000x reference)
//
#include <hip/hip_runtime.h>

// Problem constants
#define R_PIX 123904            // 352*352
#define NVIEW 8                 // B*V
#define NPIX  (R_PIX * (size_t)NVIEW)   // 991232

// Output element offsets (flat, fp32 elements)
#define OFF_MEANS  ((size_t)0)
#define OFF_COV    ((size_t)(3  * NPIX))
#define OFF_SCALES ((size_t)(12 * NPIX))
#define OFF_ROT    ((size_t)(15 * NPIX))
#define OFF_HARM   ((size_t)(19 * NPIX))
#define OFF_OPAC   ((size_t)(31 * NPIX))

// LDS: 4864 dw = 19 KiB (raw staging size 256*19), reused in two output phases:
//   phase A: means(768) + cov(2304) + scales(768) = 3840 dw
//   phase B: harm 256*13 = 3328 dw (stride 13 = 12 payload + 1 pad, odd)
#define LDS_DW   4864
#define MEANS_L  0
#define COV_L    768
#define SCALES_L 3072
#define HARM_L   0

// clang vector type for nontemporal stores (HIP float4 is a class -> rejected)
typedef float f4v __attribute__((ext_vector_type(4)));

__device__ __forceinline__ void nt_store4(float* p, float x, float y, float z, float w) {
    f4v v = { x, y, z, w };
    __builtin_nontemporal_store(v, (f4v*)p);
}
__device__ __forceinline__ void nt_store4(float* p, const float4& v) {
    nt_store4(p, v.x, v.y, v.z, v.w);
}

// Async global->LDS, 16B per lane. LDS dest is wave-uniform base + lane*16.
__device__ __forceinline__ void g2lds16(const void* g, void* l) {
    __builtin_amdgcn_global_load_lds(
        (__attribute__((address_space(1))) void*)g,
        (__attribute__((address_space(3))) void*)l,
        16, 0, 0);
}

__global__ __launch_bounds__(256) void gaussian_adapter_kernel(
    const float* __restrict__ extr,    // [8,16]
    const float* __restrict__ intr,    // [8,9]
    const float* __restrict__ coords,  // [8, R, 2]
    const float* __restrict__ depths,  // [8, R]
    const float* __restrict__ opac,    // [8, R]
    const float* __restrict__ raw,     // [8, R, 19]
    const float* __restrict__ imgs,    // [8, 3, R]
    const float* __restrict__ shmask,  // [4]
    float* __restrict__ out)
{
    const int t   = threadIdx.x;
    const int bv  = blockIdx.y;
    const int bp0 = blockIdx.x * 256;
    const size_t base_pix = (size_t)bv * R_PIX + bp0;
    const int p   = bp0 + t;
    const size_t pix = base_pix + t;

    __shared__ __align__(16) float lds[LDS_DW];

    // ---- stage raw block (256*19 dw = 1216 vec4) async straight into LDS ----
    // Lane-linear layout: vec4 slot (i*256 + t) == wave-uniform base (i*256+wave*64) + lane*16B.
    {
        const float4* g = (const float4*)(raw + base_pix * 19);
        float4* s = (float4*)lds;
        const int wave = t >> 6;
        #pragma unroll
        for (int i = 0; i < 4; i++)
            g2lds16(g + i * 256 + t, s + i * 256 + wave * 64);
        if (t < 192)                                   // waves 0..2, whole waves
            g2lds16(g + 1024 + t, s + 1024 + wave * 64);
    }

    // ---- per-view constants (uniform, scalar-cached) ----
    float Rc[3][3], tvec[3];
    {
        const float* E = extr + bv * 16;
        #pragma unroll
        for (int i = 0; i < 3; i++) {
            #pragma unroll
            for (int j = 0; j < 3; j++) Rc[i][j] = E[i * 4 + j];
            tvec[i] = E[i * 4 + 3];
        }
    }
    const float* K = intr + bv * 9;
    const float fx = K[0], cx = K[2];
    const float fy = K[4], cy = K[5];
    const float sm0 = shmask[0], sm1 = shmask[1], sm2 = shmask[2], sm3 = shmask[3];

    // ---- per-pixel streaming loads (independent of LDS; issue before barrier) ----
    const float2 uv  = ((const float2*)coords)[pix];   // 8B coalesced
    const float  dep = depths[pix];                    // stride-1
    const float  op  = opac[pix];                      // stride-1
    float im[3];
    #pragma unroll
    for (int c = 0; c < 3; c++)
        im[c] = imgs[((size_t)bv * 3 + c) * R_PIX + p];

    __syncthreads();   // staging landed

    const float* my = lds + t * 19;   // stride 19 (odd) => conflict-free lazy reads

    // ---- scales: clip(softplus(raw-4), 0.5, 15) ----
    float sc[3];
    #pragma unroll
    for (int k = 0; k < 3; k++) {
        float xv = my[k] - 4.0f;
        float sp = fmaxf(xv, 0.0f) + log1pf(expf(-fabsf(xv)));
        sc[k] = fminf(fmaxf(sp, 0.5f), 15.0f);
    }

    // ---- rotations: q / (||q|| + 1e-8) ----
    float q0 = my[3], q1 = my[4], q2 = my[5], q3 = my[6];
    {
        const float qn = q0 * q0 + q1 * q1 + q2 * q2 + q3 * q3;
        const float inorm = 1.0f / (sqrtf(qn) + 1e-8f);
        q0 *= inorm; q1 *= inorm; q2 *= inorm; q3 *= inorm;
    }

    // ---- quat -> rotation matrix ----
    const float two_s = 2.0f / (q0 * q0 + q1 * q1 + q2 * q2 + q3 * q3);
    float Rq[3][3];
    Rq[0][0] = 1.0f - two_s * (q2 * q2 + q3 * q3);
    Rq[0][1] = two_s * (q1 * q2 - q3 * q0);
    Rq[0][2] = two_s * (q1 * q3 + q2 * q0);
    Rq[1][0] = two_s * (q1 * q2 + q3 * q0);
    Rq[1][1] = 1.0f - two_s * (q1 * q1 + q3 * q3);
    Rq[1][2] = two_s * (q2 * q3 - q1 * q0);
    Rq[2][0] = two_s * (q1 * q3 - q2 * q0);
    Rq[2][1] = two_s * (q2 * q3 + q1 * q0);
    Rq[2][2] = 1.0f - two_s * (q1 * q1 + q2 * q2);

    // ---- cov = Rc (Rq diag(s^2) Rq^T) Rc^T ----
    const float s2[3] = { sc[0] * sc[0], sc[1] * sc[1], sc[2] * sc[2] };
    float cov3[3][3];
    #pragma unroll
    for (int i = 0; i < 3; i++)
        #pragma unroll
        for (int k = 0; k < 3; k++)
            cov3[i][k] = Rq[i][0] * s2[0] * Rq[k][0]
                       + Rq[i][1] * s2[1] * Rq[k][1]
                       + Rq[i][2] * s2[2] * Rq[k][2];
    float cov[3][3];
    #pragma unroll
    for (int i = 0; i < 3; i++) {
        float m0 = Rc[i][0] * cov3[0][0] + Rc[i][1] * cov3[1][0] + Rc[i][2] * cov3[2][0];
        float m1 = Rc[i][0] * cov3[0][1] + Rc[i][1] * cov3[1][1] + Rc[i][2] * cov3[2][1];
        float m2 = Rc[i][0] * cov3[0][2] + Rc[i][1] * cov3[1][2] + Rc[i][2] * cov3[2][2];
        #pragma unroll
        for (int l = 0; l < 3; l++)
            cov[i][l] = m0 * Rc[l][0] + m1 * Rc[l][1] + m2 * Rc[l][2];
    }

    // ---- means: t + Rc @ normalize(Kinv [u,v,1]) * depth ----
    float means[3];
    {
        float d0 = (uv.x - cx) / fx;
        float d1 = (uv.y - cy) / fy;
        float d2 = 1.0f;
        const float rn = 1.0f / sqrtf(d0 * d0 + d1 * d1 + d2 * d2);
        d0 *= rn; d1 *= rn; d2 *= rn;
        #pragma unroll
        for (int i = 0; i < 3; i++)
            means[i] = tvec[i] + (Rc[i][0] * d0 + Rc[i][1] * d1 + Rc[i][2] * d2) * dep;
    }

    // ---- sh = raw[7:].reshape(3,4) * sh_mask; DC += (img-0.5)/C0; harmonics ----
    float harm[3][4];
    {
        const float invC0 = 1.0f / 0.28209479177387814f;
        const int perm[3] = {1, 2, 0};
        #pragma unroll
        for (int c = 0; c < 3; c++) {
            float s1  = my[7 + c * 4 + 1] * sm1;
            float s2v = my[7 + c * 4 + 2] * sm2;
            float s3  = my[7 + c * 4 + 3] * sm3;
            harm[c][0] = my[7 + c * 4] * sm0 + (im[c] - 0.5f) * invC0;
            #pragma unroll
            for (int i = 0; i < 3; i++)
                harm[c][1 + i] = Rc[perm[i]][perm[0]] * s1
                               + Rc[perm[i]][perm[1]] * s2v
                               + Rc[perm[i]][perm[2]] * s3;
        }
    }

    __syncthreads();   // all staging reads done; LDS reusable

    // ======== phase A: means + cov + scales into LDS (3840 dw) ========
    #pragma unroll
    for (int i = 0; i < 3; i++) lds[MEANS_L + t * 3 + i] = means[i];
    #pragma unroll
    for (int i = 0; i < 3; i++)
        #pragma unroll
        for (int j = 0; j < 3; j++) lds[COV_L + t * 9 + i * 3 + j] = cov[i][j];
    #pragma unroll
    for (int i = 0; i < 3; i++) lds[SCALES_L + t * 3 + i] = sc[i];

    __syncthreads();

    // pull phase A back as coalesced vec4s into registers (no stores yet!)
    float4 mA  = make_float4(0.f, 0.f, 0.f, 0.f);
    float4 sA  = make_float4(0.f, 0.f, 0.f, 0.f);
    float4 cv2 = make_float4(0.f, 0.f, 0.f, 0.f);
    const float4 cv0 = ((const float4*)(lds + COV_L))[t];
    const float4 cv1 = ((const float4*)(lds + COV_L))[t + 256];
    if (t < 64)  cv2 = ((const float4*)(lds + COV_L))[t + 512];
    if (t < 192) {
        mA = ((const float4*)(lds + MEANS_L))[t];
        sA = ((const float4*)(lds + SCALES_L))[t];
    }

    __syncthreads();

    // ======== phase B: harm into LDS (256*13 = 3328 dw, stride 13) ========
    #pragma unroll
    for (int c = 0; c < 3; c++)
        #pragma unroll
        for (int j = 0; j < 4; j++) lds[HARM_L + t * 13 + c * 4 + j] = harm[c][j];

    __syncthreads();

    float4 hv[3];
    #pragma unroll
    for (int it = 0; it < 3; it++) {
        const int i = t + 256 * it;                 // vec4 index, 0..767
        const int px = i / 3, k = i % 3;            // 4 | 12: vec4 within one pad-13 row
        const float* s = lds + HARM_L + px * 13 + k * 4;
        hv[it] = make_float4(s[0], s[1], s[2], s[3]);
    }

    // ======== ALL global stores last: nontemporal, nothing syncs after them ========
    nt_store4(out + OFF_ROT + pix * 4, q0, q1, q2, q3);
    __builtin_nontemporal_store(op, out + OFF_OPAC + pix);
    {
        float* g = out + OFF_MEANS + base_pix * 3;
        if (t < 192) nt_store4(g + t * 4, mA);
    }
    {
        float* g = out + OFF_COV + base_pix * 9;
        nt_store4(g + t * 4, cv0);
        nt_store4(g + (t + 256) * 4, cv1);
        if (t < 64) nt_store4(g + (t + 512) * 4, cv2);
    }
    {
        float* g = out + OFF_SCALES + base_pix * 3;
        if (t < 192) nt_store4(g + t * 4, sA);
    }
    {
        float* g = out + OFF_HARM + base_pix * 12;
        #pragma unroll
        for (int it = 0; it < 3; it++)
            nt_store4(g + (t + 256 * it) * 4, hv[it]);
    }
}

extern "C" void kernel_launch(void* const* d_in, const int* in_sizes, int n_in,
                              void* d_out, int out_size, void* d_ws, size_t ws_size,
                              hipStream_t stream) {
    const float* extr   = (const float*)d_in[0];
    const float* intr   = (const float*)d_in[1];
    const float* coords = (const float*)d_in[2];
    const float* depths = (const float*)d_in[3];
    const float* opac   = (const float*)d_in[4];
    const float* raw    = (const float*)d_in[5];
    const float* imgs   = (const float*)d_in[6];
    const float* shmask = (const float*)d_in[7];
    float* out = (float*)d_out;

    dim3 grid(R_PIX / 256, NVIEW);   // 484 x 8, exact cover
    dim3 block(256);
    gaussian_adapter_kernel<<<grid, block, 0, stream>>>(
        extr, intr, coords, depths, opac, raw, imgs, shmask, out);
}

// Round 3
// 223.430 us; speedup vs baseline: 1.0051x; 1.0051x over previous
//
#include <hip/hip_runtime.h>

// Problem constants
#define R_PIX 123904            // 352*352
#define NVIEW 8                 // B*V
#define NPIX  (R_PIX * (size_t)NVIEW)   // 991232

// Output element offsets (flat, fp32 elements)
#define OFF_MEANS  ((size_t)0)
#define OFF_COV    ((size_t)(3  * NPIX))
#define OFF_SCALES ((size_t)(12 * NPIX))
#define OFF_ROT    ((size_t)(15 * NPIX))
#define OFF_HARM   ((size_t)(19 * NPIX))
#define OFF_OPAC   ((size_t)(31 * NPIX))

// Wave-private LDS slice: 1216 dw = 64 pixels * 19 dw raw staging.
// Reused by the SAME wave (no cross-wave traffic -> no output barriers):
//   phase A: means 192 + cov 576 + scales 192 = 960 dw  (fits 1216)
//   phase B: harm 64*13 = 832 dw (stride 13 = 12 payload + 1 pad, odd)
#define SLICE_DW 1216
#define LDS_DW   (SLICE_DW * 4)   // 4864 dw = 19 KiB -> 8 blocks/CU by LDS

typedef float f4v __attribute__((ext_vector_type(4)));

__device__ __forceinline__ void nt_store4(float* p, float x, float y, float z, float w) {
    f4v v = { x, y, z, w };
    __builtin_nontemporal_store(v, (f4v*)p);
}
__device__ __forceinline__ void nt_store4(float* p, const float4& v) {
    nt_store4(p, v.x, v.y, v.z, v.w);
}

// Async global->LDS, 16B per lane. LDS dest = wave-uniform base + lane*16.
__device__ __forceinline__ void g2lds16(const void* g, void* l) {
    __builtin_amdgcn_global_load_lds(
        (__attribute__((address_space(1))) void*)g,
        (__attribute__((address_space(3))) void*)l,
        16, 0, 0);
}

// In-wave LDS phase fence: drain DS ops, forbid compiler reordering across it.
__device__ __forceinline__ void lds_fence() {
    asm volatile("s_waitcnt lgkmcnt(0)" ::: "memory");
}

__global__ __launch_bounds__(256) void gaussian_adapter_kernel(
    const float* __restrict__ extr,    // [8,16]
    const float* __restrict__ intr,    // [8,9]
    const float* __restrict__ coords,  // [8, R, 2]
    const float* __restrict__ depths,  // [8, R]
    const float* __restrict__ opac,    // [8, R]
    const float* __restrict__ raw,     // [8, R, 19]
    const float* __restrict__ imgs,    // [8, 3, R]
    const float* __restrict__ shmask,  // [4]
    float* __restrict__ out)
{
    const int t    = threadIdx.x;
    const int lane = t & 63;
    const int w    = t >> 6;
    const int bv   = blockIdx.y;
    const int bp0  = blockIdx.x * 256;
    const size_t base_pix = (size_t)bv * R_PIX + bp0;
    const int p   = bp0 + t;
    const size_t pix = base_pix + t;

    __shared__ __align__(16) float lds[LDS_DW];
    float* slice = lds + w * SLICE_DW;           // wave-private 4864 B

    // ---- stage THIS WAVE's 64-pixel raw block (304 vec4) into its slice ----
    // 5 full-wave rounds; round 4 re-covers round 3's tail (same data, benign).
    {
        const float4* g = (const float4*)(raw + base_pix * 19) + w * 304;
        #pragma unroll
        for (int r = 0; r < 4; r++)
            g2lds16(g + r * 64 + lane, (char*)slice + r * 1024);
        g2lds16(g + 240 + lane, (char*)slice + 3840);
    }

    // ---- per-view constants (uniform, scalar-cached) ----
    float Rc[3][3], tvec[3];
    {
        const float* E = extr + bv * 16;
        #pragma unroll
        for (int i = 0; i < 3; i++) {
            #pragma unroll
            for (int j = 0; j < 3; j++) Rc[i][j] = E[i * 4 + j];
            tvec[i] = E[i * 4 + 3];
        }
    }
    const float* K = intr + bv * 9;
    const float fx = K[0], cx = K[2];
    const float fy = K[4], cy = K[5];
    const float sm0 = shmask[0], sm1 = shmask[1], sm2 = shmask[2], sm3 = shmask[3];

    // ---- per-pixel streaming loads (issue before the one barrier) ----
    const float2 uv  = ((const float2*)coords)[pix];
    const float  dep = depths[pix];
    const float  op  = opac[pix];
    float im[3];
    #pragma unroll
    for (int c = 0; c < 3; c++)
        im[c] = imgs[((size_t)bv * 3 + c) * R_PIX + p];

    __syncthreads();   // the ONLY block barrier: staging DMA landed

    const float* my = lds + t * 19;   // == slice + lane*19 (odd stride, conflict-free)

    // ---- read all 19 raw values (slice gets overwritten in phase A) ----
    float rg[19];
    #pragma unroll
    for (int i = 0; i < 19; i++) rg[i] = my[i];

    // ---- scales: clip(softplus(raw-4), 0.5, 15) via exp2/log2 ----
    const float LOG2E = 1.4426950408889634f;
    const float LN2   = 0.6931471805599453f;
    float sc[3];
    #pragma unroll
    for (int k = 0; k < 3; k++) {
        float xv = rg[k] - 4.0f;
        float e  = __builtin_amdgcn_exp2f(-fabsf(xv) * LOG2E);
        float sp = fmaxf(xv, 0.0f) + LN2 * __builtin_amdgcn_logf(1.0f + e);
        sc[k] = fminf(fmaxf(sp, 0.5f), 15.0f);
    }

    // ---- rotations: q * rsqrt(q.q)  (eps=1e-8 negligible vs tolerance) ----
    float q0 = rg[3], q1 = rg[4], q2 = rg[5], q3 = rg[6];
    {
        const float qn = q0 * q0 + q1 * q1 + q2 * q2 + q3 * q3;
        const float inorm = __builtin_amdgcn_rsqf(qn);
        q0 *= inorm; q1 *= inorm; q2 *= inorm; q3 *= inorm;
    }

    // ---- quat -> rotation matrix (two_s == 2 after normalization) ----
    const float two_s = 2.0f;
    float Rq[3][3];
    Rq[0][0] = 1.0f - two_s * (q2 * q2 + q3 * q3);
    Rq[0][1] = two_s * (q1 * q2 - q3 * q0);
    Rq[0][2] = two_s * (q1 * q3 + q2 * q0);
    Rq[1][0] = two_s * (q1 * q2 + q3 * q0);
    Rq[1][1] = 1.0f - two_s * (q1 * q1 + q3 * q3);
    Rq[1][2] = two_s * (q2 * q3 - q1 * q0);
    Rq[2][0] = two_s * (q1 * q3 - q2 * q0);
    Rq[2][1] = two_s * (q2 * q3 + q1 * q0);
    Rq[2][2] = 1.0f - two_s * (q1 * q1 + q2 * q2);

    // ---- cov = Rc (Rq diag(s^2) Rq^T) Rc^T ----
    const float s2[3] = { sc[0] * sc[0], sc[1] * sc[1], sc[2] * sc[2] };
    float cov3[3][3];
    #pragma unroll
    for (int i = 0; i < 3; i++)
        #pragma unroll
        for (int k = 0; k < 3; k++)
            cov3[i][k] = Rq[i][0] * s2[0] * Rq[k][0]
                       + Rq[i][1] * s2[1] * Rq[k][1]
                       + Rq[i][2] * s2[2] * Rq[k][2];
    float cov[3][3];
    #pragma unroll
    for (int i = 0; i < 3; i++) {
        float m0 = Rc[i][0] * cov3[0][0] + Rc[i][1] * cov3[1][0] + Rc[i][2] * cov3[2][0];
        float m1 = Rc[i][0] * cov3[0][1] + Rc[i][1] * cov3[1][1] + Rc[i][2] * cov3[2][1];
        float m2 = Rc[i][0] * cov3[0][2] + Rc[i][1] * cov3[1][2] + Rc[i][2] * cov3[2][2];
        #pragma unroll
        for (int l = 0; l < 3; l++)
            cov[i][l] = m0 * Rc[l][0] + m1 * Rc[l][1] + m2 * Rc[l][2];
    }

    // ---- means: t + Rc @ normalize([ (u-cx)/fx, (v-cy)/fy, 1 ]) * depth ----
    float means[3];
    {
        const float rfx = __builtin_amdgcn_rcpf(fx);
        const float rfy = __builtin_amdgcn_rcpf(fy);
        float d0 = (uv.x - cx) * rfx;
        float d1 = (uv.y - cy) * rfy;
        const float rn = __builtin_amdgcn_rsqf(d0 * d0 + d1 * d1 + 1.0f);
        d0 *= rn; d1 *= rn;
        const float d2 = rn;
        #pragma unroll
        for (int i = 0; i < 3; i++)
            means[i] = tvec[i] + (Rc[i][0] * d0 + Rc[i][1] * d1 + Rc[i][2] * d2) * dep;
    }

    // ---- harmonics: DC + D1-rotated band-1 (perm = [1,2,0]) ----
    float harm[3][4];
    {
        const float invC0 = 1.0f / 0.28209479177387814f;
        const int perm[3] = {1, 2, 0};
        #pragma unroll
        for (int c = 0; c < 3; c++) {
            float s1  = rg[7 + c * 4 + 1] * sm1;
            float s2v = rg[7 + c * 4 + 2] * sm2;
            float s3  = rg[7 + c * 4 + 3] * sm3;
            harm[c][0] = rg[7 + c * 4] * sm0 + (im[c] - 0.5f) * invC0;
            #pragma unroll
            for (int i = 0; i < 3; i++)
                harm[c][1 + i] = Rc[perm[i]][perm[0]] * s1
                               + Rc[perm[i]][perm[1]] * s2v
                               + Rc[perm[i]][perm[2]] * s3;
        }
    }

    // ---- direct stores (already dense) ----
    nt_store4(out + OFF_ROT + pix * 4, q0, q1, q2, q3);
    __builtin_nontemporal_store(op, out + OFF_OPAC + pix);

    // per-wave output chunk bases (all 16B-aligned: wpix is a multiple of 64)
    const size_t wpix = base_pix + (size_t)(w * 64);
    float* means_g = out + OFF_MEANS  + wpix * 3;
    float* cov_g   = out + OFF_COV    + wpix * 9;
    float* sc_g    = out + OFF_SCALES + wpix * 3;
    float* hm_g    = out + OFF_HARM   + wpix * 12;

    // ======== phase A (wave-private, no barrier): means+cov+scales ========
    lds_fence();   // all rg[] reads complete before slice reuse
    #pragma unroll
    for (int i = 0; i < 3; i++) slice[lane * 3 + i] = means[i];
    #pragma unroll
    for (int i = 0; i < 3; i++)
        #pragma unroll
        for (int j = 0; j < 3; j++) slice[192 + lane * 9 + i * 3 + j] = cov[i][j];
    #pragma unroll
    for (int i = 0; i < 3; i++) slice[768 + lane * 3 + i] = sc[i];

    lds_fence();   // writes visible to in-wave cross-lane reads

    // read back as aligned vec4s, store coalesced per 64-pixel chunk
    {
        const float4* sv = (const float4*)slice;
        float4 v0 = sv[lane];                    // vec4 0..63: means[0..48) | cov[0..16)
        if (lane < 48) nt_store4(means_g + 4 * lane, v0);
        else           nt_store4(cov_g + 4 * (lane - 48), v0);
        float4 v1 = sv[lane + 64];               // cov[16..80)
        nt_store4(cov_g + 4 * (lane + 16), v1);
        float4 v2 = sv[lane + 128];              // cov[80..144)
        nt_store4(cov_g + 4 * (lane + 80), v2);
        if (lane < 48) {
            float4 v3 = sv[lane + 192];          // scales[0..48)
            nt_store4(sc_g + 4 * lane, v3);
        }
    }

    // ======== phase B (wave-private, no barrier): harm, pad-13 ========
    lds_fence();   // phase-A reads complete before overwrite
    #pragma unroll
    for (int c = 0; c < 3; c++)
        #pragma unroll
        for (int j = 0; j < 4; j++) slice[lane * 13 + c * 4 + j] = harm[c][j];

    lds_fence();

    #pragma unroll
    for (int it = 0; it < 3; it++) {
        const int i = lane + 64 * it;            // vec4 index 0..191
        const int px = i / 3, k = i % 3;         // 4 | 12: vec4 within one pad-13 row
        const float* s = slice + px * 13 + k * 4;
        nt_store4(hm_g + 4 * i, s[0], s[1], s[2], s[3]);
    }
}

extern "C" void kernel_launch(void* const* d_in, const int* in_sizes, int n_in,
                              void* d_out, int out_size, void* d_ws, size_t ws_size,
                              hipStream_t stream) {
    const float* extr   = (const float*)d_in[0];
    const float* intr   = (const float*)d_in[1];
    const float* coords = (const float*)d_in[2];
    const float* depths = (const float*)d_in[3];
    const float* opac   = (const float*)d_in[4];
    const float* raw    = (const float*)d_in[5];
    const float* imgs   = (const float*)d_in[6];
    const float* shmask = (const float*)d_in[7];
    float* out = (float*)d_out;

    dim3 grid(R_PIX / 256, NVIEW);   // 484 x 8, exact cover
    dim3 block(256);
    gaussian_adapter_kernel<<<grid, block, 0, stream>>>(
        extr, intr, coords, depths, opac, raw, imgs, shmask, out);
}